// Round 4
// baseline (495.011 us; speedup 1.0000x reference)
//
#include <hip/hip_runtime.h>
#include <math.h>

typedef unsigned short u16;
typedef unsigned long long u64;
typedef __attribute__((ext_vector_type(8))) short bf16x8;
typedef __attribute__((ext_vector_type(4))) float f32x4;

#define L      1024
#define NH     8
#define DH     64
#define DR     32
#define KTS    96
#define LWIN   64
#define NXPAD  1152   // padded x-proj width: [c_kv 256|c_q 512|qi 256|ki 64|kr 32|pad 32]
#define NKV    1024   // [kc 512 | vc 512]
#define NQP    768    // [qc 512 | qrp 256]
#define CCW    352    // compact fp32 copy of cols 768..1120: [qi 256|ki 64|kr 32]

__device__ __forceinline__ u16 bf16_rn(float x) {
  unsigned u = __float_as_uint(x);
  return (u16)((u + 0x7fffu + ((u >> 16) & 1u)) >> 16);
}
__device__ __forceinline__ float bf16_tof(u16 h) {
  return __uint_as_float(((unsigned)h) << 16);
}
__device__ __forceinline__ float softplusf(float x) {
  return fmaxf(x, 0.f) + log1pf(expf(-fabsf(x)));
}
__device__ __forceinline__ f32x4 mfma16(bf16x8 a, bf16x8 b, f32x4 c) {
  return __builtin_amdgcn_mfma_f32_16x16x32_bf16(a, b, c, 0, 0, 0);
}
__device__ __forceinline__ u64 pack4(u16 a, u16 b, u16 c, u16 d) {
  return (u64)a | ((u64)b << 16) | ((u64)c << 32) | ((u64)d << 48);
}

// ---------------- weight transpose + bf16 split --------------------------
// logical W [K][N] (concat of up to 5 sources along N) -> planes [N][K] bf16
struct TSrc { const float* p; int n0, w; };

__global__ __launch_bounds__(256) void wsplit(
    TSrc s0, TSrc s1, TSrc s2, TSrc s3, TSrc s4,
    int K, u16* __restrict__ Ph, u16* __restrict__ Pm, u16* __restrict__ Pl) {
  __shared__ float tile[32][33];
  const int k0 = blockIdx.y * 32, n0 = blockIdx.x * 32;
  const int tid = threadIdx.x;
  // tile source (tiles never straddle sources; boundaries are %32)
  const float* sp = nullptr; int off = 0, w = 0;
  if (s0.p && n0 >= s0.n0 && n0 < s0.n0 + s0.w) { sp = s0.p; off = s0.n0; w = s0.w; }
  else if (s1.p && n0 >= s1.n0 && n0 < s1.n0 + s1.w) { sp = s1.p; off = s1.n0; w = s1.w; }
  else if (s2.p && n0 >= s2.n0 && n0 < s2.n0 + s2.w) { sp = s2.p; off = s2.n0; w = s2.w; }
  else if (s3.p && n0 >= s3.n0 && n0 < s3.n0 + s3.w) { sp = s3.p; off = s3.n0; w = s3.w; }
  else if (s4.p && n0 >= s4.n0 && n0 < s4.n0 + s4.w) { sp = s4.p; off = s4.n0; w = s4.w; }
  {
    const int kl = tid >> 3, n4 = (tid & 7) * 4;
    float4 v = make_float4(0.f, 0.f, 0.f, 0.f);
    if (sp) v = *(const float4*)(sp + (size_t)(k0 + kl) * w + (n0 - off) + n4);
    tile[kl][n4 + 0] = v.x; tile[kl][n4 + 1] = v.y;
    tile[kl][n4 + 2] = v.z; tile[kl][n4 + 3] = v.w;
  }
  __syncthreads();
  const int nl = tid >> 3, k4 = (tid & 7) * 4;
  u16 h[4], m[4], lo[4];
#pragma unroll
  for (int j = 0; j < 4; ++j) {
    float x = tile[k4 + j][nl];
    u16 hh = bf16_rn(x); float r = x - bf16_tof(hh);
    h[j] = hh;
    if (Pm) { u16 mm = bf16_rn(r); r = r - bf16_tof(mm); m[j] = mm; }
    lo[j] = bf16_rn(r);
  }
  const size_t o = (size_t)(n0 + nl) * K + k0 + k4;
  *(u64*)(Ph + o) = pack4(h[0], h[1], h[2], h[3]);
  if (Pm) *(u64*)(Pm + o) = pack4(m[0], m[1], m[2], m[3]);
  *(u64*)(Pl + o) = pack4(lo[0], lo[1], lo[2], lo[3]);
}

// ---------------- bf16-split MFMA GEMM -----------------------------------
// C[M,N] = A[M,K](fp32) @ B[K,N], B pre-split as [N][K] bf16 planes.
// 128x128 tile, BK=32, 4 waves (2x2), each wave 64x64 = 4x4 frags 16x16.
// LDS row stride 40 u16 (80B = 5*16B) -> conflict-free b128 frag reads.
struct GArg {
  const float* A; const u16 *B0, *B1, *B2;
  float* C; float* cc;   // cc: compact fp32 copy of cols [768,1120) (G1 only)
  int lda, ldc, K, nbn;
};

template <int NS>
__global__ __launch_bounds__(256) void mfma_gemm(GArg g0, GArg g1) {
  GArg g = (blockIdx.z == 0) ? g0 : g1;
  if ((int)blockIdx.x >= g.nbn) return;
  __shared__ u16 Al[NS * 5120];
  __shared__ u16 Bl[NS * 5120];
  const int tid = threadIdx.x;
  const int l = tid & 63, w = tid >> 6;
  const int wr = w >> 1, wc = w & 1;
  const int l15 = l & 15, l4 = l >> 4;
  const int bm = blockIdx.y * 128, bn = blockIdx.x * 128;
  const int ar = tid >> 3, ak = (tid & 7) * 4;   // A staging: rows ar+i*32
  const int brr = tid >> 2, bkc = (tid & 3) * 8; // B staging: rows brr+i*64

  f32x4 acc[4][4];
#pragma unroll
  for (int i = 0; i < 4; ++i)
#pragma unroll
    for (int j = 0; j < 4; ++j) acc[i][j] = (f32x4){0.f, 0.f, 0.f, 0.f};

  for (int k0 = 0; k0 < g.K; k0 += 32) {
    // ---- stage A (fp32 -> split bf16 planes) ----
#pragma unroll
    for (int i = 0; i < 4; ++i) {
      const int row = ar + i * 32;
      float4 v = *(const float4*)(g.A + (size_t)(bm + row) * g.lda + k0 + ak);
      float e[4] = {v.x, v.y, v.z, v.w};
      u16 h[4], m2[4], lo[4];
#pragma unroll
      for (int j = 0; j < 4; ++j) {
        float x = e[j];
        u16 hh = bf16_rn(x); float r = x - bf16_tof(hh);
        h[j] = hh;
        if (NS == 3) { u16 mm = bf16_rn(r); r = r - bf16_tof(mm); m2[j] = mm; }
        lo[j] = bf16_rn(r);
      }
      const int o = row * 40 + ak;
      *(u64*)&Al[o] = pack4(h[0], h[1], h[2], h[3]);
      if (NS == 3) {
        *(u64*)&Al[5120 + o] = pack4(m2[0], m2[1], m2[2], m2[3]);
        *(u64*)&Al[10240 + o] = pack4(lo[0], lo[1], lo[2], lo[3]);
      } else {
        *(u64*)&Al[5120 + o] = pack4(lo[0], lo[1], lo[2], lo[3]);
      }
    }
    // ---- stage B (pre-split bf16, raw copy) ----
#pragma unroll
    for (int p = 0; p < NS; ++p) {
      const u16* Bp = (p == 0) ? g.B0 : (p == 1 ? g.B1 : g.B2);
#pragma unroll
      for (int i = 0; i < 2; ++i) {
        const int row = brr + i * 64;
        uint4 v = *(const uint4*)(Bp + (size_t)(bn + row) * g.K + k0 + bkc);
        *(uint4*)&Bl[p * 5120 + row * 40 + bkc] = v;
      }
    }
    __syncthreads();
    // ---- fragments + MFMA ----
    bf16x8 af[NS][4], bf[NS][4];
#pragma unroll
    for (int f = 0; f < 4; ++f) {
      const int arow = wr * 64 + f * 16 + l15;
      const int brow = wc * 64 + f * 16 + l15;
#pragma unroll
      for (int p = 0; p < NS; ++p) {
        af[p][f] = *(const bf16x8*)&Al[p * 5120 + arow * 40 + l4 * 8];
        bf[p][f] = *(const bf16x8*)&Bl[p * 5120 + brow * 40 + l4 * 8];
      }
    }
#pragma unroll
    for (int fm = 0; fm < 4; ++fm)
#pragma unroll
      for (int fn = 0; fn < 4; ++fn) {
        f32x4 c = acc[fm][fn];
        c = mfma16(af[0][fm], bf[0][fn], c);
        c = mfma16(af[0][fm], bf[1][fn], c);
        c = mfma16(af[1][fm], bf[0][fn], c);
        if (NS == 3) {
          c = mfma16(af[0][fm], bf[2][fn], c);
          c = mfma16(af[2][fm], bf[0][fn], c);
          c = mfma16(af[1][fm], bf[1][fn], c);
        }
        acc[fm][fn] = c;
      }
    __syncthreads();
  }
  // ---- epilogue: C/D layout col=l&15, row=(l>>4)*4+reg ----
#pragma unroll
  for (int fm = 0; fm < 4; ++fm)
#pragma unroll
    for (int j = 0; j < 4; ++j) {
      const int row = bm + wr * 64 + fm * 16 + l4 * 4 + j;
      float* crow = g.C + (size_t)row * g.ldc;
      float* ccrow = g.cc ? (g.cc + (size_t)row * CCW) : nullptr;
#pragma unroll
      for (int fn = 0; fn < 4; ++fn) {
        const int col = bn + wc * 64 + fn * 16 + l15;
        const float val = acc[fm][fn][j];
        crow[col] = val;
        if (ccrow && (unsigned)(col - 768) < (unsigned)CCW) ccrow[col - 768] = val;
      }
    }
}

// ------------- LightningIndexer scores + TokenSelector top-k -----------------
// qiki row: [qi 256 | ki 64 | kr 32], stride CCW. Exact jax.lax.top_k ordering.
__global__ __launch_bounds__(256) void indexer_topk(
    const float* __restrict__ qiki, const float* __restrict__ idx_w,
    int* __restrict__ idx_sel) {
  const int bt = blockIdx.x;
  const int b = bt >> 10;
  const int t = bt & 1023;
  const int tid = threadIdx.x;
  int* out = idx_sel + (size_t)bt * KTS;
  if (t < LWIN) {
    if (tid < KTS) out[tid] = tid;
    return;
  }
  if (tid < 64) out[tid] = t - 63 + tid;
  const int nf = t - 63;  // finite candidates: s = 0 .. t-64
  __shared__ __align__(16) float qis[256];
  __shared__ float wsh[4];
  __shared__ u64 keys[960];
  __shared__ u64 wred[4];
  qis[tid] = qiki[(size_t)bt * CCW + tid];
  if (tid < 4) wsh[tid] = idx_w[tid];
  __syncthreads();
  const float* kib = qiki + (size_t)b * L * CCW + 256;
  for (int s = tid; s < nf; s += 256) {
    const float* kr = kib + (size_t)s * CCW;
    float a0 = 0.f, a1 = 0.f, a2 = 0.f, a3 = 0.f;
#pragma unroll
    for (int d = 0; d < 64; d += 4) {
      float4 kv = *(const float4*)(kr + d);
      float4 q0 = *(const float4*)&qis[d];
      float4 q1 = *(const float4*)&qis[64 + d];
      float4 q2 = *(const float4*)&qis[128 + d];
      float4 q3 = *(const float4*)&qis[192 + d];
      a0 += q0.x * kv.x + q0.y * kv.y + q0.z * kv.z + q0.w * kv.w;
      a1 += q1.x * kv.x + q1.y * kv.y + q1.z * kv.z + q1.w * kv.w;
      a2 += q2.x * kv.x + q2.y * kv.y + q2.z * kv.z + q2.w * kv.w;
      a3 += q3.x * kv.x + q3.y * kv.y + q3.z * kv.z + q3.w * kv.w;
    }
    float I = wsh[0] * fmaxf(a0, 0.f) + wsh[1] * fmaxf(a1, 0.f)
            + wsh[2] * fmaxf(a2, 0.f) + wsh[3] * fmaxf(a3, 0.f);
    unsigned ib = __float_as_uint(I);
    if (ib == 0x80000000u) ib = 0u;                      // -0.0 -> +0.0
    ib = (ib & 0x80000000u) ? ~ib : (ib | 0x80000000u);  // monotone map
    keys[s] = ((u64)ib << 32) | (u64)(0xFFFFFFFFu - (unsigned)s);
  }
  __syncthreads();
  const int topM = nf < 32 ? nf : 32;
  for (int it = 0; it < topM; ++it) {
    u64 best = 0ull;
    for (int s = tid; s < nf; s += 256) {
      u64 v = keys[s];
      if (v > best) best = v;
    }
    for (int off = 32; off > 0; off >>= 1) {
      u64 o = __shfl_down(best, off);
      if (o > best) best = o;
    }
    if ((tid & 63) == 0) wred[tid >> 6] = best;
    __syncthreads();
    if (tid == 0) {
      u64 m = wred[0];
      if (wred[1] > m) m = wred[1];
      if (wred[2] > m) m = wred[2];
      if (wred[3] > m) m = wred[3];
      unsigned s = 0xFFFFFFFFu - (unsigned)(m & 0xFFFFFFFFull);
      out[64 + it] = (int)s;
      keys[s] = 0ull;
    }
    __syncthreads();
  }
  for (int j = tid; j < 32 - topM; j += 256) out[64 + topM + j] = t + 1 + j;
}

// ----------------------- sparse attention per (b,t) --------------------------
__global__ __launch_bounds__(256) void attn_kernel(
    const float* __restrict__ qproj, const float* __restrict__ kvproj,
    const float* __restrict__ qiki, const int* __restrict__ idx_sel,
    const float* __restrict__ raw_delta, float* __restrict__ attn_out) {
  const int bt = blockIdx.x;
  const int b = bt >> 10;
  const int t = bt & 1023;
  const int tid = threadIdx.x;

  __shared__ __align__(16) float qcs[NH * DH];   // 512
  __shared__ __align__(16) float qrs[NH * DR];   // 256
  __shared__ __align__(16) float krs[KTS * DR];  // 3072
  __shared__ float scoresS[NH][KTS];
  __shared__ int selS[KTS];
  __shared__ float thetav[16], deltav[16];
  __shared__ float mu[NH * DR];

  const float* qrow = qproj + (size_t)bt * NQP;
  qcs[tid] = qrow[tid];
  qcs[256 + tid] = qrow[256 + tid];
  mu[tid] = softplusf(qrow[512 + tid]);
  if (tid < KTS) selS[tid] = idx_sel[(size_t)bt * KTS + tid];
  if (tid < 16) {
    thetav[tid] = (float)(1.0 / pow(10000.0, (double)tid / 16.0));
    float r = raw_delta[tid];
    deltav[tid] = -6.2831853071795864769f * (1.f / (1.f + expf(-r)));
  }
  __syncthreads();

  if (tid < 128) {
    int h = tid >> 4, i = tid & 15;
    float ang = (float)t * thetav[i] + deltav[i];
    float c = cosf(ang), s = sinf(ang);
    float m1 = mu[h * DR + i], m2 = mu[h * DR + 16 + i];
    qrs[h * DR + i] = m1 * c - m2 * s;
    qrs[h * DR + 16 + i] = m1 * s + m2 * c;
  }
  const float* krb = qiki + (size_t)b * L * CCW + 320;
  for (int e = tid; e < KTS * 16; e += 256) {
    int k = e >> 4, i = e & 15;
    int s = selS[k];
    float x1 = krb[(size_t)s * CCW + i];
    float x2 = krb[(size_t)s * CCW + 16 + i];
    float m1 = softplusf(x1), m2 = softplusf(x2);
    float ang = (float)k * thetav[i] + deltav[i];
    float c = cosf(ang), sn = sinf(ang);
    krs[k * DR + i] = m1 * c - m2 * sn;
    krs[k * DR + 16 + i] = m1 * sn + m2 * c;
  }
  __syncthreads();

  const float scale = 0.10206207261596575f;  // (64+32)^-0.5
  const int h = tid >> 5;
  const int l = tid & 31;
  const float2 qv = *(const float2*)&qcs[h * DH + 2 * l];
  float2 qr2 = make_float2(0.f, 0.f);
  if (l < 16) qr2 = *(const float2*)&qrs[h * DR + 2 * l];
  const float* kvb = kvproj + (size_t)b * L * NKV;
#pragma unroll 4
  for (int k = 0; k < KTS; ++k) {
    const float2 kv = *(const float2*)(kvb + (size_t)selS[k] * NKV + 2 * tid);
    float p = qv.x * kv.x + qv.y * kv.y;
    if (l < 16) {
      const float2 kr2 = *(const float2*)&krs[k * DR + 2 * l];
      p += qr2.x * kr2.x + qr2.y * kr2.y;
    }
#pragma unroll
    for (int off = 16; off > 0; off >>= 1) p += __shfl_xor(p, off, 32);
    if (l == 0) scoresS[h][k] = p * scale;
  }
  __syncthreads();

  {
    float s0 = scoresS[h][l], s1 = scoresS[h][l + 32], s2 = scoresS[h][l + 64];
    float mx = fmaxf(fmaxf(s0, s1), s2);
#pragma unroll
    for (int off = 16; off > 0; off >>= 1) mx = fmaxf(mx, __shfl_xor(mx, off, 32));
    float e0 = expf(s0 - mx), e1 = expf(s1 - mx), e2 = expf(s2 - mx);
    float sum = e0 + e1 + e2;
#pragma unroll
    for (int off = 16; off > 0; off >>= 1) sum += __shfl_xor(sum, off, 32);
    float inv = 1.f / sum;
    scoresS[h][l] = e0 * inv;
    scoresS[h][l + 32] = e1 * inv;
    scoresS[h][l + 64] = e2 * inv;
  }
  __syncthreads();

  float2 acc = make_float2(0.f, 0.f);
#pragma unroll 4
  for (int k = 0; k < KTS; ++k) {
    const float2 v = *(const float2*)(kvb + (size_t)selS[k] * NKV + 512 + 2 * tid);
    const float w = scoresS[h][k];
    acc.x += w * v.x;
    acc.y += w * v.y;
  }
  *(float2*)(attn_out + (size_t)bt * 512 + 2 * tid) = acc;
}

// -----------------------------------------------------------------------------
extern "C" void kernel_launch(void* const* d_in, const int* in_sizes, int n_in,
                              void* d_out, int out_size, void* d_ws, size_t ws_size,
                              hipStream_t stream) {
  const float* x      = (const float*)d_in[0];
  const float* W_dkv  = (const float*)d_in[1];
  const float* W_uk   = (const float*)d_in[2];
  const float* W_uv   = (const float*)d_in[3];
  const float* W_dq   = (const float*)d_in[4];
  const float* W_uq   = (const float*)d_in[5];
  const float* W_qr   = (const float*)d_in[6];
  const float* W_kr   = (const float*)d_in[7];
  const float* W_out  = (const float*)d_in[8];
  const float* idx_wq = (const float*)d_in[9];
  const float* idx_wk = (const float*)d_in[10];
  const float* idx_w  = (const float*)d_in[11];
  const float* raw_dl = (const float*)d_in[12];
  float* out = (float*)d_out;

  const int M = 2 * L;  // 2048
  // ---- workspace carve-up (u16 planes first, then fp32 buffers) ----
  u16* BxT_h  = (u16*)d_ws;                     // 1152*1024
  u16* BxT_m  = BxT_h + 1152 * 1024;
  u16* BxT_l  = BxT_m + 1152 * 1024;
  u16* BkvT_h = BxT_l + 1152 * 1024;            // 1024*256
  u16* BkvT_l = BkvT_h + 1024 * 256;
  u16* BqT_h  = BkvT_l + 1024 * 256;            // 768*512
  u16* BqT_l  = BqT_h + 768 * 512;
  u16* WoT_h  = BqT_l + 768 * 512;              // 1024*512
  u16* WoT_l  = WoT_h + 1024 * 512;
  float* xproj  = (float*)(WoT_l + 1024 * 512); // 2048*1152
  float* qiki   = xproj + (size_t)M * NXPAD;    // 2048*352
  float* kvproj = qiki + (size_t)M * CCW;       // 2048*1024
  float* qproj  = kvproj + (size_t)M * NKV;     // 2048*768
  float* ao     = qproj + (size_t)M * NQP;      // 2048*512
  int* sel      = (int*)(ao + (size_t)M * 512); // 2048*96

  dim3 blk(256);
  TSrc z = {nullptr, 0, 0};
  // ---- weight prep: transpose + split ----
  {
    TSrc a = {W_dkv, 0, 256}, bq = {W_dq, 256, 512}, c = {idx_wq, 768, 256},
         d = {idx_wk, 1024, 64}, e = {W_kr, 1088, 32};
    hipLaunchKernelGGL(wsplit, dim3(NXPAD / 32, 1024 / 32), blk, 0, stream,
                       a, bq, c, d, e, 1024, BxT_h, BxT_m, BxT_l);
  }
  {
    TSrc a = {W_uk, 0, 512}, bq = {W_uv, 512, 512};
    hipLaunchKernelGGL(wsplit, dim3(NKV / 32, 256 / 32), blk, 0, stream,
                       a, bq, z, z, z, 256, BkvT_h, (u16*)nullptr, BkvT_l);
  }
  {
    TSrc a = {W_uq, 0, 512}, bq = {W_qr, 512, 256};
    hipLaunchKernelGGL(wsplit, dim3(NQP / 32, 512 / 32), blk, 0, stream,
                       a, bq, z, z, z, 512, BqT_h, (u16*)nullptr, BqT_l);
  }
  {
    TSrc a = {W_out, 0, 1024};
    hipLaunchKernelGGL(wsplit, dim3(1024 / 32, 512 / 32), blk, 0, stream,
                       a, z, z, z, z, 512, WoT_h, (u16*)nullptr, WoT_l);
  }
  // ---- G1: xproj = x @ Bx (x3 precision; also compact qi/ki/kr copy) ----
  {
    GArg g1 = {x, BxT_h, BxT_m, BxT_l, xproj, qiki, 1024, NXPAD, 1024, NXPAD / 128};
    hipLaunchKernelGGL(mfma_gemm<3>, dim3(NXPAD / 128, M / 128, 1), blk, 0, stream,
                       g1, g1);
  }
  hipLaunchKernelGGL(indexer_topk, dim3(M), blk, 0, stream, qiki, idx_w, sel);
  // ---- G2+G3 fused via gridDim.z: kvproj (K=256) and qproj (K=512) ----
  {
    GArg g2 = {xproj, BkvT_h, BkvT_l, nullptr, kvproj, nullptr,
               NXPAD, NKV, 256, NKV / 128};
    GArg g3 = {xproj + 256, BqT_h, BqT_l, nullptr, qproj, nullptr,
               NXPAD, NQP, 512, NQP / 128};
    hipLaunchKernelGGL(mfma_gemm<2>, dim3(NKV / 128, M / 128, 2), blk, 0, stream,
                       g2, g3);
  }
  hipLaunchKernelGGL(attn_kernel, dim3(M), blk, 0, stream,
                     qproj, kvproj, qiki, sel, raw_dl, ao);
  // ---- G5: out = ao @ W_out ----
  {
    GArg g5 = {ao, WoT_h, WoT_l, nullptr, out, nullptr, 512, 1024, 512, 1024 / 128};
    hipLaunchKernelGGL(mfma_gemm<2>, dim3(1024 / 128, M / 128, 1), blk, 0, stream,
                       g5, g5);
  }
}

// Round 5
// 390.862 us; speedup vs baseline: 1.2665x; 1.2665x over previous
//
#include <hip/hip_runtime.h>
#include <math.h>

typedef unsigned short u16;
typedef unsigned long long u64;
typedef __attribute__((ext_vector_type(8))) short bf16x8;
typedef __attribute__((ext_vector_type(4))) float f32x4;

#define L      1024
#define NH     8
#define DH     64
#define DR     32
#define KTS    96
#define LWIN   64
#define NXPAD  1152   // padded x-proj width: [c_kv 256|c_q 512|qi 256|ki 64|kr 32|pad 32]
#define NKV    1024   // [kc 512 | vc 512]
#define NQP    768    // [qc 512 | qrp 256]
#define CCW    352    // compact fp32 copy of cols 768..1120: [qi 256|ki 64|kr 32]

__device__ __forceinline__ u16 bf16_rn(float x) {
  unsigned u = __float_as_uint(x);
  return (u16)((u + 0x7fffu + ((u >> 16) & 1u)) >> 16);
}
__device__ __forceinline__ float bf16_tof(u16 h) {
  return __uint_as_float(((unsigned)h) << 16);
}
__device__ __forceinline__ float softplusf(float x) {
  return fmaxf(x, 0.f) + log1pf(expf(-fabsf(x)));
}
__device__ __forceinline__ f32x4 mfma16(bf16x8 a, bf16x8 b, f32x4 c) {
  return __builtin_amdgcn_mfma_f32_16x16x32_bf16(a, b, c, 0, 0, 0);
}
__device__ __forceinline__ u64 pack4(u16 a, u16 b, u16 c, u16 d) {
  return (u64)a | ((u64)b << 16) | ((u64)c << 32) | ((u64)d << 48);
}
__device__ __forceinline__ u64 umax64(u64 a, u64 b) { return a > b ? a : b; }

// ---------------- weight transpose + bf16 split --------------------------
// logical W [K][N] (concat of up to 5 sources along N) -> planes [N][K] bf16
struct TSrc { const float* p; int n0, w; };

__global__ __launch_bounds__(256) void wsplit(
    TSrc s0, TSrc s1, TSrc s2, TSrc s3, TSrc s4,
    int K, u16* __restrict__ Ph, u16* __restrict__ Pm, u16* __restrict__ Pl) {
  __shared__ float tile[32][33];
  const int k0 = blockIdx.y * 32, n0 = blockIdx.x * 32;
  const int tid = threadIdx.x;
  // tile source (tiles never straddle sources; boundaries are %32)
  const float* sp = nullptr; int off = 0, w = 0;
  if (s0.p && n0 >= s0.n0 && n0 < s0.n0 + s0.w) { sp = s0.p; off = s0.n0; w = s0.w; }
  else if (s1.p && n0 >= s1.n0 && n0 < s1.n0 + s1.w) { sp = s1.p; off = s1.n0; w = s1.w; }
  else if (s2.p && n0 >= s2.n0 && n0 < s2.n0 + s2.w) { sp = s2.p; off = s2.n0; w = s2.w; }
  else if (s3.p && n0 >= s3.n0 && n0 < s3.n0 + s3.w) { sp = s3.p; off = s3.n0; w = s3.w; }
  else if (s4.p && n0 >= s4.n0 && n0 < s4.n0 + s4.w) { sp = s4.p; off = s4.n0; w = s4.w; }
  {
    const int kl = tid >> 3, n4 = (tid & 7) * 4;
    float4 v = make_float4(0.f, 0.f, 0.f, 0.f);
    if (sp) v = *(const float4*)(sp + (size_t)(k0 + kl) * w + (n0 - off) + n4);
    tile[kl][n4 + 0] = v.x; tile[kl][n4 + 1] = v.y;
    tile[kl][n4 + 2] = v.z; tile[kl][n4 + 3] = v.w;
  }
  __syncthreads();
  const int nl = tid >> 3, k4 = (tid & 7) * 4;
  u16 h[4], m[4], lo[4];
#pragma unroll
  for (int j = 0; j < 4; ++j) {
    float x = tile[k4 + j][nl];
    u16 hh = bf16_rn(x); float r = x - bf16_tof(hh);
    h[j] = hh;
    if (Pm) { u16 mm = bf16_rn(r); r = r - bf16_tof(mm); m[j] = mm; }
    lo[j] = bf16_rn(r);
  }
  const size_t o = (size_t)(n0 + nl) * K + k0 + k4;
  *(u64*)(Ph + o) = pack4(h[0], h[1], h[2], h[3]);
  if (Pm) *(u64*)(Pm + o) = pack4(m[0], m[1], m[2], m[3]);
  *(u64*)(Pl + o) = pack4(lo[0], lo[1], lo[2], lo[3]);
}

// ---------------- bf16-split MFMA GEMM -----------------------------------
// C[M,N] = A[M,K](fp32) @ B[K,N], B pre-split as [N][K] bf16 planes.
// 128x128 tile, BK=32, 4 waves (2x2), each wave 64x64 = 4x4 frags 16x16.
// LDS row stride 40 u16 (80B = 5*16B) -> conflict-free b128 frag reads.
struct GArg {
  const float* A; const u16 *B0, *B1, *B2;
  float* C; float* cc;   // cc: compact fp32 copy of cols [768,1120) (G1 only)
  int lda, ldc, K, nbn;
};

template <int NS>
__global__ __launch_bounds__(256) void mfma_gemm(GArg g0, GArg g1) {
  GArg g = (blockIdx.z == 0) ? g0 : g1;
  if ((int)blockIdx.x >= g.nbn) return;
  __shared__ u16 Al[NS * 5120];
  __shared__ u16 Bl[NS * 5120];
  const int tid = threadIdx.x;
  const int l = tid & 63, w = tid >> 6;
  const int wr = w >> 1, wc = w & 1;
  const int l15 = l & 15, l4 = l >> 4;
  const int bm = blockIdx.y * 128, bn = blockIdx.x * 128;
  const int ar = tid >> 3, ak = (tid & 7) * 4;   // A staging: rows ar+i*32
  const int brr = tid >> 2, bkc = (tid & 3) * 8; // B staging: rows brr+i*64

  f32x4 acc[4][4];
#pragma unroll
  for (int i = 0; i < 4; ++i)
#pragma unroll
    for (int j = 0; j < 4; ++j) acc[i][j] = (f32x4){0.f, 0.f, 0.f, 0.f};

  for (int k0 = 0; k0 < g.K; k0 += 32) {
    // ---- stage A (fp32 -> split bf16 planes) ----
#pragma unroll
    for (int i = 0; i < 4; ++i) {
      const int row = ar + i * 32;
      float4 v = *(const float4*)(g.A + (size_t)(bm + row) * g.lda + k0 + ak);
      float e[4] = {v.x, v.y, v.z, v.w};
      u16 h[4], m2[4], lo[4];
#pragma unroll
      for (int j = 0; j < 4; ++j) {
        float x = e[j];
        u16 hh = bf16_rn(x); float r = x - bf16_tof(hh);
        h[j] = hh;
        if (NS == 3) { u16 mm = bf16_rn(r); r = r - bf16_tof(mm); m2[j] = mm; }
        lo[j] = bf16_rn(r);
      }
      const int o = row * 40 + ak;
      *(u64*)&Al[o] = pack4(h[0], h[1], h[2], h[3]);
      if (NS == 3) {
        *(u64*)&Al[5120 + o] = pack4(m2[0], m2[1], m2[2], m2[3]);
        *(u64*)&Al[10240 + o] = pack4(lo[0], lo[1], lo[2], lo[3]);
      } else {
        *(u64*)&Al[5120 + o] = pack4(lo[0], lo[1], lo[2], lo[3]);
      }
    }
    // ---- stage B (pre-split bf16, raw copy) ----
#pragma unroll
    for (int p = 0; p < NS; ++p) {
      const u16* Bp = (p == 0) ? g.B0 : (p == 1 ? g.B1 : g.B2);
#pragma unroll
      for (int i = 0; i < 2; ++i) {
        const int row = brr + i * 64;
        uint4 v = *(const uint4*)(Bp + (size_t)(bn + row) * g.K + k0 + bkc);
        *(uint4*)&Bl[p * 5120 + row * 40 + bkc] = v;
      }
    }
    __syncthreads();
    // ---- fragments + MFMA ----
    bf16x8 af[NS][4], bf[NS][4];
#pragma unroll
    for (int f = 0; f < 4; ++f) {
      const int arow = wr * 64 + f * 16 + l15;
      const int brow = wc * 64 + f * 16 + l15;
#pragma unroll
      for (int p = 0; p < NS; ++p) {
        af[p][f] = *(const bf16x8*)&Al[p * 5120 + arow * 40 + l4 * 8];
        bf[p][f] = *(const bf16x8*)&Bl[p * 5120 + brow * 40 + l4 * 8];
      }
    }
#pragma unroll
    for (int fm = 0; fm < 4; ++fm)
#pragma unroll
      for (int fn = 0; fn < 4; ++fn) {
        f32x4 c = acc[fm][fn];
        c = mfma16(af[0][fm], bf[0][fn], c);
        c = mfma16(af[0][fm], bf[1][fn], c);
        c = mfma16(af[1][fm], bf[0][fn], c);
        if (NS == 3) {
          c = mfma16(af[0][fm], bf[2][fn], c);
          c = mfma16(af[2][fm], bf[0][fn], c);
          c = mfma16(af[1][fm], bf[1][fn], c);
        }
        acc[fm][fn] = c;
      }
    __syncthreads();
  }
  // ---- epilogue: C/D layout col=l&15, row=(l>>4)*4+reg ----
#pragma unroll
  for (int fm = 0; fm < 4; ++fm)
#pragma unroll
    for (int j = 0; j < 4; ++j) {
      const int row = bm + wr * 64 + fm * 16 + l4 * 4 + j;
      float* crow = g.C + (size_t)row * g.ldc;
      float* ccrow = g.cc ? (g.cc + (size_t)row * CCW) : nullptr;
#pragma unroll
      for (int fn = 0; fn < 4; ++fn) {
        const int col = bn + wc * 64 + fn * 16 + l15;
        const float val = acc[fm][fn][j];
        crow[col] = val;
        if (ccrow && (unsigned)(col - 768) < (unsigned)CCW) ccrow[col - 768] = val;
      }
    }
}

// ------------- LightningIndexer scores + TokenSelector top-k -----------------
// One WAVE per (b,t) row; 4 rows per block. Keys live in registers (15 u64
// slots per lane: candidate s = j*64+lane). Exact jax.lax.top_k ordering via
// monotone key (value_bits<<32)|(~s); selection = 32 wave-level max rounds
// with per-lane cached max, no block barriers after the initial one.
#define KPL 15  // ceil(960/64)

__global__ __launch_bounds__(256) void indexer_topk(
    const float* __restrict__ qiki, const float* __restrict__ idx_w,
    int* __restrict__ idx_sel) {
  const int wave = threadIdx.x >> 6;
  const int lane = threadIdx.x & 63;
  const int bt = blockIdx.x * 4 + wave;
  const int b = bt >> 10;
  const int t = bt & 1023;
  int* out = idx_sel + (size_t)bt * KTS;

  __shared__ __align__(16) float qsh[4][256];
  // load this wave's q row (unconditionally; row always exists)
  *(float4*)&qsh[wave][lane * 4] =
      *(const float4*)(qiki + (size_t)bt * CCW + lane * 4);
  const float w0 = idx_w[0], w1 = idx_w[1], w2 = idx_w[2], w3 = idx_w[3];
  __syncthreads();  // single barrier, reached by all threads

  if (t < LWIN) {
    out[lane] = lane;
    if (lane < 32) out[64 + lane] = 64 + lane;
    return;
  }
  out[lane] = t - 63 + lane;
  const int nf = t - 63;  // finite candidates: s = 0 .. t-64

  const float* kib = qiki + (size_t)b * L * CCW + 256;
  const float* qw = qsh[wave];
  u64 key[KPL];
#pragma unroll
  for (int j = 0; j < KPL; ++j) {
    u64 k = 0ull;
    const int s = j * 64 + lane;
    if (s < nf) {
      const float* kr = kib + (size_t)s * CCW;
      float a0 = 0.f, a1 = 0.f, a2 = 0.f, a3 = 0.f;
#pragma unroll 4
      for (int d = 0; d < 64; d += 4) {
        float4 kv = *(const float4*)(kr + d);
        float4 q0 = *(const float4*)&qw[d];
        float4 q1 = *(const float4*)&qw[64 + d];
        float4 q2 = *(const float4*)&qw[128 + d];
        float4 q3 = *(const float4*)&qw[192 + d];
        a0 += q0.x * kv.x + q0.y * kv.y + q0.z * kv.z + q0.w * kv.w;
        a1 += q1.x * kv.x + q1.y * kv.y + q1.z * kv.z + q1.w * kv.w;
        a2 += q2.x * kv.x + q2.y * kv.y + q2.z * kv.z + q2.w * kv.w;
        a3 += q3.x * kv.x + q3.y * kv.y + q3.z * kv.z + q3.w * kv.w;
      }
      float I = w0 * fmaxf(a0, 0.f) + w1 * fmaxf(a1, 0.f)
              + w2 * fmaxf(a2, 0.f) + w3 * fmaxf(a3, 0.f);
      unsigned ib = __float_as_uint(I);
      if (ib == 0x80000000u) ib = 0u;                      // -0.0 -> +0.0
      ib = (ib & 0x80000000u) ? ~ib : (ib | 0x80000000u);  // monotone map
      k = ((u64)ib << 32) | (u64)(0xFFFFFFFFu - (unsigned)s);
    }
    key[j] = k;
  }

  // per-lane cached max
  u64 lm = key[0];
#pragma unroll
  for (int j = 1; j < KPL; ++j) lm = umax64(lm, key[j]);

  const int topM = nf < 32 ? nf : 32;
  for (int it = 0; it < topM; ++it) {
    u64 m = lm;
#pragma unroll
    for (int off = 32; off > 0; off >>= 1) m = umax64(m, __shfl_xor(m, off));
    if (lane == 0)
      out[64 + it] = (int)(0xFFFFFFFFu - (unsigned)(m & 0xFFFFFFFFull));
    if (lm == m) {  // unique winner lane: clear slot, recompute local max
#pragma unroll
      for (int j = 0; j < KPL; ++j)
        if (key[j] == m) key[j] = 0ull;
      lm = key[0];
#pragma unroll
      for (int j = 1; j < KPL; ++j) lm = umax64(lm, key[j]);
    }
  }
  if (lane < 32 - topM) out[64 + topM + lane] = t + 1 + lane;
}

// ----------------------- sparse attention per (b,t) --------------------------
__global__ __launch_bounds__(256) void attn_kernel(
    const float* __restrict__ qproj, const float* __restrict__ kvproj,
    const float* __restrict__ qiki, const int* __restrict__ idx_sel,
    const float* __restrict__ raw_delta, float* __restrict__ attn_out) {
  const int bt = blockIdx.x;
  const int b = bt >> 10;
  const int t = bt & 1023;
  const int tid = threadIdx.x;

  __shared__ __align__(16) float qcs[NH * DH];   // 512
  __shared__ __align__(16) float qrs[NH * DR];   // 256
  __shared__ __align__(16) float krs[KTS * DR];  // 3072
  __shared__ float scoresS[NH][KTS];
  __shared__ int selS[KTS];
  __shared__ float thetav[16], deltav[16];
  __shared__ float mu[NH * DR];

  const float* qrow = qproj + (size_t)bt * NQP;
  qcs[tid] = qrow[tid];
  qcs[256 + tid] = qrow[256 + tid];
  mu[tid] = softplusf(qrow[512 + tid]);
  if (tid < KTS) selS[tid] = idx_sel[(size_t)bt * KTS + tid];
  if (tid < 16) {
    thetav[tid] = (float)(1.0 / pow(10000.0, (double)tid / 16.0));
    float r = raw_delta[tid];
    deltav[tid] = -6.2831853071795864769f * (1.f / (1.f + expf(-r)));
  }
  __syncthreads();

  if (tid < 128) {
    int h = tid >> 4, i = tid & 15;
    float ang = (float)t * thetav[i] + deltav[i];
    float c = cosf(ang), s = sinf(ang);
    float m1 = mu[h * DR + i], m2 = mu[h * DR + 16 + i];
    qrs[h * DR + i] = m1 * c - m2 * s;
    qrs[h * DR + 16 + i] = m1 * s + m2 * c;
  }
  const float* krb = qiki + (size_t)b * L * CCW + 320;
  for (int e = tid; e < KTS * 16; e += 256) {
    int k = e >> 4, i = e & 15;
    int s = selS[k];
    float x1 = krb[(size_t)s * CCW + i];
    float x2 = krb[(size_t)s * CCW + 16 + i];
    float m1 = softplusf(x1), m2 = softplusf(x2);
    float ang = (float)k * thetav[i] + deltav[i];
    float c = cosf(ang), sn = sinf(ang);
    krs[k * DR + i] = m1 * c - m2 * sn;
    krs[k * DR + 16 + i] = m1 * sn + m2 * c;
  }
  __syncthreads();

  const float scale = 0.10206207261596575f;  // (64+32)^-0.5
  const int h = tid >> 5;
  const int l = tid & 31;
  const float2 qv = *(const float2*)&qcs[h * DH + 2 * l];
  float2 qr2 = make_float2(0.f, 0.f);
  if (l < 16) qr2 = *(const float2*)&qrs[h * DR + 2 * l];
  const float* kvb = kvproj + (size_t)b * L * NKV;
#pragma unroll 4
  for (int k = 0; k < KTS; ++k) {
    const float2 kv = *(const float2*)(kvb + (size_t)selS[k] * NKV + 2 * tid);
    float p = qv.x * kv.x + qv.y * kv.y;
    if (l < 16) {
      const float2 kr2 = *(const float2*)&krs[k * DR + 2 * l];
      p += qr2.x * kr2.x + qr2.y * kr2.y;
    }
#pragma unroll
    for (int off = 16; off > 0; off >>= 1) p += __shfl_xor(p, off, 32);
    if (l == 0) scoresS[h][k] = p * scale;
  }
  __syncthreads();

  {
    float s0 = scoresS[h][l], s1 = scoresS[h][l + 32], s2 = scoresS[h][l + 64];
    float mx = fmaxf(fmaxf(s0, s1), s2);
#pragma unroll
    for (int off = 16; off > 0; off >>= 1) mx = fmaxf(mx, __shfl_xor(mx, off, 32));
    float e0 = expf(s0 - mx), e1 = expf(s1 - mx), e2 = expf(s2 - mx);
    float sum = e0 + e1 + e2;
#pragma unroll
    for (int off = 16; off > 0; off >>= 1) sum += __shfl_xor(sum, off, 32);
    float inv = 1.f / sum;
    scoresS[h][l] = e0 * inv;
    scoresS[h][l + 32] = e1 * inv;
    scoresS[h][l + 64] = e2 * inv;
  }
  __syncthreads();

  float2 acc = make_float2(0.f, 0.f);
#pragma unroll 4
  for (int k = 0; k < KTS; ++k) {
    const float2 v = *(const float2*)(kvb + (size_t)selS[k] * NKV + 512 + 2 * tid);
    const float w = scoresS[h][k];
    acc.x += w * v.x;
    acc.y += w * v.y;
  }
  *(float2*)(attn_out + (size_t)bt * 512 + 2 * tid) = acc;
}

// -----------------------------------------------------------------------------
extern "C" void kernel_launch(void* const* d_in, const int* in_sizes, int n_in,
                              void* d_out, int out_size, void* d_ws, size_t ws_size,
                              hipStream_t stream) {
  const float* x      = (const float*)d_in[0];
  const float* W_dkv  = (const float*)d_in[1];
  const float* W_uk   = (const float*)d_in[2];
  const float* W_uv   = (const float*)d_in[3];
  const float* W_dq   = (const float*)d_in[4];
  const float* W_uq   = (const float*)d_in[5];
  const float* W_qr   = (const float*)d_in[6];
  const float* W_kr   = (const float*)d_in[7];
  const float* W_out  = (const float*)d_in[8];
  const float* idx_wq = (const float*)d_in[9];
  const float* idx_wk = (const float*)d_in[10];
  const float* idx_w  = (const float*)d_in[11];
  const float* raw_dl = (const float*)d_in[12];
  float* out = (float*)d_out;

  const int M = 2 * L;  // 2048
  // ---- workspace carve-up (u16 planes first, then fp32 buffers) ----
  u16* BxT_h  = (u16*)d_ws;                     // 1152*1024
  u16* BxT_m  = BxT_h + 1152 * 1024;
  u16* BxT_l  = BxT_m + 1152 * 1024;
  u16* BkvT_h = BxT_l + 1152 * 1024;            // 1024*256
  u16* BkvT_l = BkvT_h + 1024 * 256;
  u16* BqT_h  = BkvT_l + 1024 * 256;            // 768*512
  u16* BqT_l  = BqT_h + 768 * 512;
  u16* WoT_h  = BqT_l + 768 * 512;              // 1024*512
  u16* WoT_l  = WoT_h + 1024 * 512;
  float* xproj  = (float*)(WoT_l + 1024 * 512); // 2048*1152
  float* qiki   = xproj + (size_t)M * NXPAD;    // 2048*352
  float* kvproj = qiki + (size_t)M * CCW;       // 2048*1024
  float* qproj  = kvproj + (size_t)M * NKV;     // 2048*768
  float* ao     = qproj + (size_t)M * NQP;      // 2048*512
  int* sel      = (int*)(ao + (size_t)M * 512); // 2048*96

  dim3 blk(256);
  TSrc z = {nullptr, 0, 0};
  // ---- weight prep: transpose + split ----
  {
    TSrc a = {W_dkv, 0, 256}, bq = {W_dq, 256, 512}, c = {idx_wq, 768, 256},
         d = {idx_wk, 1024, 64}, e = {W_kr, 1088, 32};
    hipLaunchKernelGGL(wsplit, dim3(NXPAD / 32, 1024 / 32), blk, 0, stream,
                       a, bq, c, d, e, 1024, BxT_h, BxT_m, BxT_l);
  }
  {
    TSrc a = {W_uk, 0, 512}, bq = {W_uv, 512, 512};
    hipLaunchKernelGGL(wsplit, dim3(NKV / 32, 256 / 32), blk, 0, stream,
                       a, bq, z, z, z, 256, BkvT_h, (u16*)nullptr, BkvT_l);
  }
  {
    TSrc a = {W_uq, 0, 512}, bq = {W_qr, 512, 256};
    hipLaunchKernelGGL(wsplit, dim3(NQP / 32, 512 / 32), blk, 0, stream,
                       a, bq, z, z, z, 512, BqT_h, (u16*)nullptr, BqT_l);
  }
  {
    TSrc a = {W_out, 0, 1024};
    hipLaunchKernelGGL(wsplit, dim3(1024 / 32, 512 / 32), blk, 0, stream,
                       a, z, z, z, z, 512, WoT_h, (u16*)nullptr, WoT_l);
  }
  // ---- G1: xproj = x @ Bx (x3 precision; also compact qi/ki/kr copy) ----
  {
    GArg g1 = {x, BxT_h, BxT_m, BxT_l, xproj, qiki, 1024, NXPAD, 1024, NXPAD / 128};
    hipLaunchKernelGGL(mfma_gemm<3>, dim3(NXPAD / 128, M / 128, 1), blk, 0, stream,
                       g1, g1);
  }
  hipLaunchKernelGGL(indexer_topk, dim3(M / 4), blk, 0, stream, qiki, idx_w, sel);
  // ---- G2+G3 fused via gridDim.z: kvproj (K=256) and qproj (K=512) ----
  {
    GArg g2 = {xproj, BkvT_h, BkvT_l, nullptr, kvproj, nullptr,
               NXPAD, NKV, 256, NKV / 128};
    GArg g3 = {xproj + 256, BqT_h, BqT_l, nullptr, qproj, nullptr,
               NXPAD, NQP, 512, NQP / 128};
    hipLaunchKernelGGL(mfma_gemm<2>, dim3(NKV / 128, M / 128, 2), blk, 0, stream,
                       g2, g3);
  }
  hipLaunchKernelGGL(attn_kernel, dim3(M), blk, 0, stream,
                     qproj, kvproj, qiki, sel, raw_dl, ao);
  // ---- G5: out = ao @ W_out ----
  {
    GArg g5 = {ao, WoT_h, WoT_l, nullptr, out, nullptr, 512, 1024, 512, 1024 / 128};
    hipLaunchKernelGGL(mfma_gemm<2>, dim3(1024 / 128, M / 128, 1), blk, 0, stream,
                       g5, g5);
  }
}